// Round 3
// baseline (822.196 us; speedup 1.0000x reference)
//
#include <hip/hip_runtime.h>
#include <hip/hip_cooperative_groups.h>

namespace cg = cooperative_groups;

#define BB 4
#define NN 4
#define TT 4
#define AA 128
#define DD 64
#define HWD 36864              // 192*192
#define NG (BB * TT * AA)      // 2048
#define CHUNKS 128
#define CPTS (HWD / CHUNKS)    // 288
#define NBLK (BB * TT * CHUNKS)  // 2048

__device__ __constant__ int c_ti[4] = {0, 0, 0, 1};
__device__ __constant__ int c_tj[4] = {1, 1, 2, 2};
__device__ __constant__ int c_tk[4] = {2, 3, 3, 3};

// One cooperative kernel, 2048 blocks x 128 threads.
// Block (bt, chunk): bt = blockIdx>>7, chunk = blockIdx&127.
// Phases separated by grid.sync():
//   1. scan1: stage chunk of image tj into LDS (with |p|^2), 128 queries =
//      anchors of image ti; write per-chunk partial (key, argmin).
//   2. combine1 (blocks 0..15): serial over 128 chunks, coalesced; write
//      min_ij, idx_j.
//   3. scan2: same with image tk, queries = pts_j[idx_j].
//   4. combine2+pass3 (blocks 0..15): combine in-register, dki vs anchors,
//      feature SE, per-(b,t) reduce.
//   5. final (block 0): 16 -> scalar.
__global__ __launch_bounds__(128, 4) void
fused_kernel(const float* __restrict__ pts,
             const float* __restrict__ feats,
             const int* __restrict__ anchor_idx,
             float* __restrict__ pkey,
             int* __restrict__ pidx,
             float* __restrict__ min_ij,
             int* __restrict__ idx_j,
             float* __restrict__ loss_bt,
             float* __restrict__ batch_ok,
             float* __restrict__ out) {
#pragma clang fp contract(off)
    cg::grid_group grid = cg::this_grid();
    const int tid = threadIdx.x;
    const int chunk = blockIdx.x & (CHUNKS - 1);
    const int bt = blockIdx.x >> 7;
    const int t = bt & 3;
    const int b = bt >> 2;
    const int g = bt * AA + tid;

    __shared__ float4 spts[CPTS];        // 4.6 KB
    __shared__ float aps[AA][3];         // 1.5 KB
    __shared__ float sred[2][AA];        // 1.0 KB

    // ---------------- Phase 1: scan1 ----------------
    {
        const int simg = c_tj[t];
        const float* src = pts + ((long)(b * NN + simg) * HWD + chunk * CPTS) * 3;
        for (int p = tid; p < CPTS; p += 128) {
            const float x = src[p * 3 + 0];
            const float y = src[p * 3 + 1];
            const float z = src[p * 3 + 2];
            spts[p] = make_float4(x, y, z, x * x + y * y + z * z);
        }
        __syncthreads();
        const int qpix = anchor_idx[g];
        const float* qp = pts + ((long)(b * NN + c_ti[t]) * HWD + qpix) * 3;
        const float m2x = -2.0f * qp[0];
        const float m2y = -2.0f * qp[1];
        const float m2z = -2.0f * qp[2];
        float best = 3.4e38f;
        int besti = 0;
#pragma unroll 4
        for (int p = 0; p < CPTS; ++p) {
            const float4 P = spts[p];
            const float key =
                fmaf(P.x, m2x, fmaf(P.y, m2y, fmaf(P.z, m2z, P.w)));
            if (key < best) { best = key; besti = p; }  // first occurrence
        }
        pkey[chunk * NG + g] = best;
        pidx[chunk * NG + g] = chunk * CPTS + besti;
    }
    grid.sync();

    // ---------------- Phase 2: combine1 (blocks 0..15) ----------------
    if (blockIdx.x < 16) {
        const int bt2 = blockIdx.x;
        const int t2 = bt2 & 3;
        const int b2 = bt2 >> 2;
        const int g2 = bt2 * AA + tid;
        float best = 3.4e38f;
        int besti = 0;
        for (int c = 0; c < CHUNKS; ++c) {
            const float k = pkey[c * NG + g2];
            const int i = pidx[c * NG + g2];
            if (k < best) { best = k; besti = i; }  // ascending c => first occ
        }
        const int qpix = anchor_idx[g2];
        const float* qp = pts + ((long)(b2 * NN + c_ti[t2]) * HWD + qpix) * 3;
        const float x = qp[0], y = qp[1], z = qp[2];
        min_ij[g2] = sqrtf(fmaxf(best + (x * x + y * y + z * z), 0.0f));
        idx_j[g2] = besti;
    }
    grid.sync();

    // ---------------- Phase 3: scan2 ----------------
    {
        const int simg = c_tk[t];
        const float* src = pts + ((long)(b * NN + simg) * HWD + chunk * CPTS) * 3;
        for (int p = tid; p < CPTS; p += 128) {
            const float x = src[p * 3 + 0];
            const float y = src[p * 3 + 1];
            const float z = src[p * 3 + 2];
            spts[p] = make_float4(x, y, z, x * x + y * y + z * z);
        }
        __syncthreads();
        const int qpix = idx_j[g];
        const float* qp = pts + ((long)(b * NN + c_tj[t]) * HWD + qpix) * 3;
        const float m2x = -2.0f * qp[0];
        const float m2y = -2.0f * qp[1];
        const float m2z = -2.0f * qp[2];
        float best = 3.4e38f;
        int besti = 0;
#pragma unroll 4
        for (int p = 0; p < CPTS; ++p) {
            const float4 P = spts[p];
            const float key =
                fmaf(P.x, m2x, fmaf(P.y, m2y, fmaf(P.z, m2z, P.w)));
            if (key < best) { best = key; besti = p; }
        }
        pkey[chunk * NG + g] = best;
        pidx[chunk * NG + g] = chunk * CPTS + besti;
    }
    grid.sync();

    // ---------------- Phase 4: combine2 + pass3 (blocks 0..15) ----------
    if (blockIdx.x < 16) {
        const int bt2 = blockIdx.x;
        const int t2 = bt2 & 3;
        const int b2 = bt2 >> 2;
        const int g2 = bt2 * AA + tid;
        const int i = c_ti[t2];
        const int k = c_tk[t2];

        // combine2 in-register
        float bjk = 3.4e38f;
        int ik = 0;
        for (int c = 0; c < CHUNKS; ++c) {
            const float kk = pkey[c * NG + g2];
            const int ii = pidx[c * NG + g2];
            if (kk < bjk) { bjk = kk; ik = ii; }
        }
        const int qpj = idx_j[g2];
        const float* jp = pts + ((long)(b2 * NN + c_tj[t2]) * HWD + qpj) * 3;
        const float jx = jp[0], jy = jp[1], jz = jp[2];
        const float min_jk = sqrtf(fmaxf(bjk + (jx * jx + jy * jy + jz * jz), 0.0f));

        // dki: anchor points to LDS, query = pkc
        const int ai = anchor_idx[g2];
        const float* ap = pts + ((long)(b2 * NN + i) * HWD + ai) * 3;
        aps[tid][0] = ap[0];
        aps[tid][1] = ap[1];
        aps[tid][2] = ap[2];
        const float* kp = pts + ((long)(b2 * NN + k) * HWD + ik) * 3;
        const float kx = kp[0], ky = kp[1], kz = kp[2];
        const float sk = kx * kx + ky * ky + kz * kz;
        __syncthreads();

        float best = 3.4e38f;
        int besti = 0;
        for (int a2 = 0; a2 < AA; ++a2) {
            const float qx = aps[a2][0], qy = aps[a2][1], qz = aps[a2][2];
            const float s2 = qx * qx + qy * qy + qz * qz;
            const float dot = kx * qx + ky * qy + kz * qz;
            const float d2 = (sk + s2) - 2.0f * dot;
            if (d2 < best) { best = d2; besti = a2; }
        }
        const float min_ki = sqrtf(fmaxf(best, 0.0f));

        const int valid =
            (min_ij[g2] < 0.3f) && (min_jk < 0.3f) && (min_ki < 0.3f);

        // feat_ret: reference quirk — raw pixel index besti in [0,128)
        const float* fr = feats + ((long)(b2 * NN + i) * HWD + besti) * DD;
        const float* fa = feats + ((long)(b2 * NN + i) * HWD + ai) * DD;

        float snr = 0.0f, sna = 0.0f;
        for (int d = 0; d < DD; ++d) {
            const float x = fr[d];
            snr += x * x;
        }
        for (int d = 0; d < DD; ++d) {
            const float y = fa[d];
            sna += y * y;
        }
        const float nr = fmaxf(sqrtf(snr), 1e-12f);
        const float na = fmaxf(sqrtf(sna), 1e-12f);
        float se = 0.0f;
        for (int d = 0; d < DD; ++d) {
            const float x = fr[d] / nr - fa[d] / na;
            se += x * x;
        }

        sred[0][tid] = (float)valid;
        sred[1][tid] = valid ? se : 0.0f;
        __syncthreads();
        for (int s = 64; s > 0; s >>= 1) {
            if (tid < s) {
                sred[0][tid] += sred[0][tid + s];
                sred[1][tid] += sred[1][tid + s];
            }
            __syncthreads();
        }
        if (tid == 0) {
            const float cnt = sred[0][0];
            loss_bt[bt2] = (cnt > 0.0f)
                               ? sred[1][0] / (fmaxf(cnt, 1.0f) * (float)DD)
                               : 0.0f;
            batch_ok[bt2] = (cnt >= 5.0f) ? 1.0f : 0.0f;
        }
    }
    grid.sync();

    // ---------------- Phase 5: final ----------------
    if (blockIdx.x == 0 && tid == 0) {
        float s = 0.0f;
        for (int tt = 0; tt < TT; ++tt) {
            float tc = 0.0f, sl = 0.0f;
            for (int bb = 0; bb < BB; ++bb) {
                const float ok = batch_ok[bb * TT + tt];
                tc += ok;
                sl += loss_bt[bb * TT + tt] * ok;
            }
            s += (tc > 0.0f) ? sl / fmaxf(tc, 1.0f) : 0.0f;
        }
        out[0] = s / (float)TT;
    }
}

extern "C" void kernel_launch(void* const* d_in, const int* in_sizes, int n_in,
                              void* d_out, int out_size, void* d_ws,
                              size_t ws_size, hipStream_t stream) {
    const float* feats = (const float*)d_in[0];   // (B,N,H,W,D) f32
    const float* pts = (const float*)d_in[1];     // (B,N,H,W,3) f32
    const int* anchor = (const int*)d_in[2];      // (B,T,A) i32
    float* out = (float*)d_out;

    float* ws = (float*)d_ws;
    float* pkey = ws;                               // CHUNKS*NG f32 (1 MB)
    int* pidx = (int*)(ws + CHUNKS * NG);           // CHUNKS*NG i32
    float* min_ij = ws + 2 * CHUNKS * NG;           // NG f32
    int* idx_j = (int*)(ws + 2 * CHUNKS * NG + NG); // NG i32
    float* loss_bt = ws + 2 * CHUNKS * NG + 2 * NG; // 16 f32
    float* batch_ok = loss_bt + 16;                 // 16 f32

    void* args[] = {(void*)&pts,     (void*)&feats,   (void*)&anchor,
                    (void*)&pkey,    (void*)&pidx,    (void*)&min_ij,
                    (void*)&idx_j,   (void*)&loss_bt, (void*)&batch_ok,
                    (void*)&out};
    hipLaunchCooperativeKernel((const void*)fused_kernel, dim3(NBLK),
                               dim3(128), args, 0, stream);
}

// Round 4
// 109.192 us; speedup vs baseline: 7.5298x; 7.5298x over previous
//
#include <hip/hip_runtime.h>

#define BB 4
#define NN 4
#define TT 4
#define AA 128
#define DD 64
#define HWD 36864              // 192*192
#define NG (BB * TT * AA)      // 2048
#define CHUNKS 64
#define CPTS (HWD / CHUNKS)    // 576
#define NBLK (BB * TT * CHUNKS)  // 1024

__device__ __constant__ int c_ti[4] = {0, 0, 0, 1};
__device__ __constant__ int c_tj[4] = {1, 1, 2, 2};
__device__ __constant__ int c_tk[4] = {2, 3, 3, 3};

// ---------------------------------------------------------------------------
// K1: block (bt, chunk).  Stage CPTS points of image tj into LDS with |p|^2;
// 128 threads = 128 anchor queries of image ti.  Key = s2 - 2*dot (order-
// equivalent to d2; per-query constant sq added at combine time).
// Writes per-chunk partials (plain stores, no init required).
// ---------------------------------------------------------------------------
__global__ __launch_bounds__(128, 4) void
scan1_kernel(const float* __restrict__ pts,
             const int* __restrict__ anchor_idx,
             float* __restrict__ pkey1,
             int* __restrict__ pidx1) {
#pragma clang fp contract(off)
    const int chunk = blockIdx.x & (CHUNKS - 1);
    const int bt = blockIdx.x >> 6;
    const int t = bt & 3;
    const int b = bt >> 2;
    const int tid = threadIdx.x;
    const int g = bt * AA + tid;

    __shared__ float4 spts[CPTS];
    {
        const float* src =
            pts + ((long)(b * NN + c_tj[t]) * HWD + chunk * CPTS) * 3;
        for (int p = tid; p < CPTS; p += 128) {
            const float x = src[p * 3 + 0];
            const float y = src[p * 3 + 1];
            const float z = src[p * 3 + 2];
            spts[p] = make_float4(x, y, z, x * x + y * y + z * z);
        }
    }
    __syncthreads();

    const int qpix = anchor_idx[g];
    const float* qp = pts + ((long)(b * NN + c_ti[t]) * HWD + qpix) * 3;
    const float m2x = -2.0f * qp[0];
    const float m2y = -2.0f * qp[1];
    const float m2z = -2.0f * qp[2];

    float best = 3.4e38f;
    int besti = 0;
#pragma unroll 4
    for (int p = 0; p < CPTS; ++p) {
        const float4 P = spts[p];
        const float key = fmaf(P.x, m2x, fmaf(P.y, m2y, fmaf(P.z, m2z, P.w)));
        if (key < best) { best = key; besti = p; }   // ascending -> first occ
    }
    pkey1[chunk * NG + g] = best;
    pidx1[chunk * NG + g] = chunk * CPTS + besti;
}

// ---------------------------------------------------------------------------
// K2: block (bt, chunk).  Each thread combines its query's 64 chunk partials
// in-register (coalesced [chunk][g] reads; redundant across chunk-blocks but
// deterministic).  chunk==0 blocks store min_ij / idx_j.  Then scan image tk
// with query = pts_j[idx_j].  Block 0 zeroes K3's finish counter.
// ---------------------------------------------------------------------------
__global__ __launch_bounds__(128, 4) void
scan2_kernel(const float* __restrict__ pts,
             const int* __restrict__ anchor_idx,
             const float* __restrict__ pkey1,
             const int* __restrict__ pidx1,
             float* __restrict__ min_ij,
             int* __restrict__ idx_j_out,
             float* __restrict__ pkey2,
             int* __restrict__ pidx2,
             int* __restrict__ ctr) {
#pragma clang fp contract(off)
    const int chunk = blockIdx.x & (CHUNKS - 1);
    const int bt = blockIdx.x >> 6;
    const int t = bt & 3;
    const int b = bt >> 2;
    const int tid = threadIdx.x;
    const int g = bt * AA + tid;

    if (blockIdx.x == 0 && tid == 0) ctr[0] = 0;

    // combine1 (in-register)
    float bkey = 3.4e38f;
    int bidx = 0;
    for (int c = 0; c < CHUNKS; ++c) {
        const float k = pkey1[c * NG + g];
        const int i = pidx1[c * NG + g];
        if (k < bkey) { bkey = k; bidx = i; }   // ascending c -> first occ
    }
    const int idx_j = bidx;

    if (chunk == 0) {
        const int qpix = anchor_idx[g];
        const float* qp = pts + ((long)(b * NN + c_ti[t]) * HWD + qpix) * 3;
        const float x = qp[0], y = qp[1], z = qp[2];
        min_ij[g] = sqrtf(fmaxf(bkey + (x * x + y * y + z * z), 0.0f));
        idx_j_out[g] = idx_j;
    }

    __shared__ float4 spts[CPTS];
    {
        const float* src =
            pts + ((long)(b * NN + c_tk[t]) * HWD + chunk * CPTS) * 3;
        for (int p = tid; p < CPTS; p += 128) {
            const float x = src[p * 3 + 0];
            const float y = src[p * 3 + 1];
            const float z = src[p * 3 + 2];
            spts[p] = make_float4(x, y, z, x * x + y * y + z * z);
        }
    }
    __syncthreads();

    const float* qp = pts + ((long)(b * NN + c_tj[t]) * HWD + idx_j) * 3;
    const float m2x = -2.0f * qp[0];
    const float m2y = -2.0f * qp[1];
    const float m2z = -2.0f * qp[2];

    float best = 3.4e38f;
    int besti = 0;
#pragma unroll 4
    for (int p = 0; p < CPTS; ++p) {
        const float4 P = spts[p];
        const float key = fmaf(P.x, m2x, fmaf(P.y, m2y, fmaf(P.z, m2z, P.w)));
        if (key < best) { best = key; besti = p; }
    }
    pkey2[chunk * NG + g] = best;
    pidx2[chunk * NG + g] = chunk * CPTS + besti;
}

// ---------------------------------------------------------------------------
// K3: 16 blocks (one per bt), 128 threads (one per anchor).
//   combine2 -> min_jk/idx_k; dki vs LDS-staged anchors; feature SE;
//   block reduce -> loss_bt/batch_ok; finish-counter; last block -> scalar.
// ---------------------------------------------------------------------------
__global__ __launch_bounds__(128) void
pass3_kernel(const float* __restrict__ pts,
             const float* __restrict__ feats,
             const int* __restrict__ anchor_idx,
             const float* __restrict__ min_ij,
             const int* __restrict__ idx_j_in,
             const float* __restrict__ pkey2,
             const int* __restrict__ pidx2,
             float* __restrict__ loss_bt,
             float* __restrict__ batch_ok,
             int* __restrict__ ctr,
             float* __restrict__ out) {
#pragma clang fp contract(off)
    const int bt = blockIdx.x;
    const int t = bt & 3;
    const int b = bt >> 2;
    const int i = c_ti[t];
    const int k = c_tk[t];
    const int tid = threadIdx.x;
    const int g = bt * AA + tid;

    // combine2
    float bkey = 3.4e38f;
    int ik = 0;
    for (int c = 0; c < CHUNKS; ++c) {
        const float kk = pkey2[c * NG + g];
        const int ii = pidx2[c * NG + g];
        if (kk < bkey) { bkey = kk; ik = ii; }
    }
    const int qpj = idx_j_in[g];
    const float* jp = pts + ((long)(b * NN + c_tj[t]) * HWD + qpj) * 3;
    const float jx = jp[0], jy = jp[1], jz = jp[2];
    const float min_jk =
        sqrtf(fmaxf(bkey + (jx * jx + jy * jy + jz * jz), 0.0f));

    // dki
    const int ai = anchor_idx[g];
    const float* ap = pts + ((long)(b * NN + i) * HWD + ai) * 3;
    __shared__ float aps[AA][3];
    aps[tid][0] = ap[0];
    aps[tid][1] = ap[1];
    aps[tid][2] = ap[2];
    const float* kp = pts + ((long)(b * NN + k) * HWD + ik) * 3;
    const float kx = kp[0], ky = kp[1], kz = kp[2];
    const float sk = kx * kx + ky * ky + kz * kz;
    __syncthreads();

    float best = 3.4e38f;
    int besti = 0;
    for (int a2 = 0; a2 < AA; ++a2) {
        const float qx = aps[a2][0], qy = aps[a2][1], qz = aps[a2][2];
        const float s2 = qx * qx + qy * qy + qz * qz;
        const float dot = kx * qx + ky * qy + kz * qz;
        const float d2 = (sk + s2) - 2.0f * dot;
        if (d2 < best) { best = d2; besti = a2; }
    }
    const float min_ki = sqrtf(fmaxf(best, 0.0f));

    const int valid =
        (min_ij[g] < 0.3f) && (min_jk < 0.3f) && (min_ki < 0.3f);

    // feat_ret: reference quirk — raw pixel index besti in [0,128)
    const float* fr = feats + ((long)(b * NN + i) * HWD + besti) * DD;
    const float* fa = feats + ((long)(b * NN + i) * HWD + ai) * DD;
    float snr = 0.0f, sna = 0.0f;
    for (int d = 0; d < DD; ++d) { const float x = fr[d]; snr += x * x; }
    for (int d = 0; d < DD; ++d) { const float y = fa[d]; sna += y * y; }
    const float nr = fmaxf(sqrtf(snr), 1e-12f);
    const float na = fmaxf(sqrtf(sna), 1e-12f);
    float se = 0.0f;
    for (int d = 0; d < DD; ++d) {
        const float x = fr[d] / nr - fa[d] / na;
        se += x * x;
    }

    __shared__ float sred[2][AA];
    sred[0][tid] = (float)valid;
    sred[1][tid] = valid ? se : 0.0f;
    __syncthreads();
    for (int s = 64; s > 0; s >>= 1) {
        if (tid < s) {
            sred[0][tid] += sred[0][tid + s];
            sred[1][tid] += sred[1][tid + s];
        }
        __syncthreads();
    }
    if (tid == 0) {
        const float cnt = sred[0][0];
        const float lbt = (cnt > 0.0f)
                              ? sred[1][0] / (fmaxf(cnt, 1.0f) * (float)DD)
                              : 0.0f;
        const float ok = (cnt >= 5.0f) ? 1.0f : 0.0f;
        atomicExch(&loss_bt[bt], lbt);     // device-scope write-through
        atomicExch(&batch_ok[bt], ok);
        __threadfence();
        const int old = atomicAdd(ctr, 1);
        if (old == 15) {
            // last block: all 16 results are globally visible
            float s = 0.0f;
            for (int tt = 0; tt < TT; ++tt) {
                float tc = 0.0f, sl = 0.0f;
                for (int bb = 0; bb < BB; ++bb) {
                    const float okv = atomicAdd(&batch_ok[bb * TT + tt], 0.0f);
                    const float lv = atomicAdd(&loss_bt[bb * TT + tt], 0.0f);
                    tc += okv;
                    sl += lv * okv;
                }
                s += (tc > 0.0f) ? sl / fmaxf(tc, 1.0f) : 0.0f;
            }
            out[0] = s / (float)TT;
        }
    }
}

extern "C" void kernel_launch(void* const* d_in, const int* in_sizes, int n_in,
                              void* d_out, int out_size, void* d_ws,
                              size_t ws_size, hipStream_t stream) {
    const float* feats = (const float*)d_in[0];   // (B,N,H,W,D) f32
    const float* pts = (const float*)d_in[1];     // (B,N,H,W,3) f32
    const int* anchor = (const int*)d_in[2];      // (B,T,A) i32
    float* out = (float*)d_out;

    float* ws = (float*)d_ws;
    float* pkey1 = ws;                               // CHUNKS*NG f32 (512KB)
    int* pidx1 = (int*)(ws + CHUNKS * NG);
    float* pkey2 = ws + 2 * CHUNKS * NG;
    int* pidx2 = (int*)(ws + 3 * CHUNKS * NG);
    float* min_ij = ws + 4 * CHUNKS * NG;            // NG
    int* idx_j = (int*)(min_ij + NG);                // NG
    float* loss_bt = min_ij + 2 * NG;                // 16
    float* batch_ok = loss_bt + 16;                  // 16
    int* ctr = (int*)(batch_ok + 16);                // 1

    scan1_kernel<<<NBLK, 128, 0, stream>>>(pts, anchor, pkey1, pidx1);
    scan2_kernel<<<NBLK, 128, 0, stream>>>(pts, anchor, pkey1, pidx1, min_ij,
                                           idx_j, pkey2, pidx2, ctr);
    pass3_kernel<<<BB * TT, 128, 0, stream>>>(pts, feats, anchor, min_ij,
                                              idx_j, pkey2, pidx2, loss_bt,
                                              batch_ok, ctr, out);
}